// Round 2
// baseline (964.589 us; speedup 1.0000x reference)
//
#include <hip/hip_runtime.h>
#include <hip/hip_bf16.h>
#include <math.h>

#define B_SZ 16
#define SEQ 2048
#define D_MODEL 512
#define D_INNER 1024
#define D_STATE 16
#define D_CONV 4
#define NSEG 64
#define SEGLEN (SEQ / NSEG)   // 32
#define LOG2E 1.44269504f

typedef __attribute__((ext_vector_type(8))) short short8;
typedef __attribute__((ext_vector_type(4))) float f32x4;
typedef const __attribute__((address_space(1))) void* gas_ptr;
typedef __attribute__((address_space(3))) void* las_ptr;

__device__ __forceinline__ float bf2f(unsigned int bits16) {
    union { unsigned int i; float f; } v; v.i = bits16 << 16; return v.f;
}
__device__ __forceinline__ unsigned short f2bf(float f) {
    union { float f; unsigned int i; } v; v.f = f;
    unsigned int r = v.i + 0x7FFFu + ((v.i >> 16) & 1u);
    return (unsigned short)(r >> 16);
}
__device__ __forceinline__ void async_g2l(const void* g, void* l) {
    __builtin_amdgcn_global_load_lds((gas_ptr)g, (las_ptr)l, 16, 0, 0);
}
__device__ __forceinline__ float fast_exp2(float x) { return __builtin_amdgcn_exp2f(x); }
__device__ __forceinline__ float fast_rcp(float x)  { return __builtin_amdgcn_rcpf(x); }
__device__ __forceinline__ float clamp3(float x, float lo, float hi) {
    return __builtin_amdgcn_fmed3f(x, lo, hi);
}
__device__ __forceinline__ float silu(float x) {
    return x * fast_rcp(1.f + fast_exp2(-x * LOG2E));
}

// ---------------------------------------------------------------------------
// f32 -> bf16 cast (4 elements/thread), optional clip to [-10,10]
// ---------------------------------------------------------------------------
__global__ __launch_bounds__(256) void cast_bf16(
    const float4* __restrict__ in, ushort4* __restrict__ out, int n4, int do_clip)
{
    int i = blockIdx.x * 256 + threadIdx.x;
    if (i >= n4) return;
    float4 v = in[i];
    if (do_clip) {
        v.x = clamp3(v.x, -10.f, 10.f);
        v.y = clamp3(v.y, -10.f, 10.f);
        v.z = clamp3(v.z, -10.f, 10.f);
        v.w = clamp3(v.w, -10.f, 10.f);
    }
    ushort4 o;
    o.x = f2bf(v.x); o.y = f2bf(v.y); o.z = f2bf(v.z); o.w = f2bf(v.w);
    out[i] = o;
}

// ---------------------------------------------------------------------------
// bf16 MFMA NT-GEMM: C[M,N] = A[M,K] @ Bw[N,K]^T, 128x128 tile, BK=32,
// 4 waves (2x2 of 64x64), 16x16x32 bf16 MFMA, double-buffered LDS
// (STAGE(next) issued before the MFMA cluster; 1 barrier per k-iter).
// XCD-aware blockIdx swizzle + XOR-swizzled 16B LDS slots.
// Epilogue: +bias[n], +add[m,n] (optionally clipped), f32 or bf16 output.
// ---------------------------------------------------------------------------
__global__ __launch_bounds__(256) void gemm_bf16(
    const unsigned short* __restrict__ A, const unsigned short* __restrict__ Bw,
    void* __restrict__ C, int K, int ldc, int nbn_shift,
    const float* __restrict__ bias,
    const float* __restrict__ add, int ldadd, int clip_add, int out_bf16)
{
    __shared__ unsigned short As[2][128][32];
    __shared__ unsigned short Bs[2][128][32];
    const int h = blockIdx.x;
    const int xk = h & 7;
    const int qb = h >> 3;
    const int bn = (qb & ((1 << nbn_shift) - 1)) * 128;
    const int bm = ((qb >> nbn_shift) * 8 + xk) * 128;
    const int tid = threadIdx.x;
    const int wv = tid >> 6;
    const int l  = tid & 63;
    const int lr = l >> 2;
    const int lc = l & 3;
    const int wm = (wv >> 1) * 64;
    const int wn = (wv & 1) * 64;
    const int r16 = l & 15;
    const int q   = l >> 4;
    const int gsw = (lc - ((lr >> 1) & 3)) & 3;
    const int ssw = ((q + ((r16 >> 1) & 3)) & 3) * 8;

    f32x4 acc[4][4];
    #pragma unroll
    for (int i = 0; i < 4; i++)
        #pragma unroll
        for (int j = 0; j < 4; j++)
            acc[i][j] = (f32x4){0.f, 0.f, 0.f, 0.f};

#define STAGE(kk, bb) { \
        const int k0_ = (kk) * 32; \
        _Pragma("unroll") \
        for (int p_ = 0; p_ < 2; p_++) { \
            const int row_ = wv * 32 + p_ * 16 + lr; \
            async_g2l((const char*)A + (((size_t)(bm + row_)) * K + k0_ + gsw * 8) * 2, \
                      (char*)&As[bb][0][0] + (wv * 32 + p_ * 16) * 64); \
            async_g2l((const char*)Bw + (((size_t)(bn + row_)) * K + k0_ + gsw * 8) * 2, \
                      (char*)&Bs[bb][0][0] + (wv * 32 + p_ * 16) * 64); \
        } }

    const int nk = K >> 5;
    STAGE(0, 0);
    __syncthreads();

    for (int kk = 0; kk < nk; kk++) {
        const int cur = kk & 1;
        if (kk + 1 < nk) STAGE(kk + 1, cur ^ 1);

        short8 af[4], bfv[4];
        #pragma unroll
        for (int i = 0; i < 4; i++) {
            af[i]  = *(const short8*)&As[cur][wm + i * 16 + r16][ssw];
            bfv[i] = *(const short8*)&Bs[cur][wn + i * 16 + r16][ssw];
        }
        #pragma unroll
        for (int i = 0; i < 4; i++)
            #pragma unroll
            for (int j = 0; j < 4; j++)
                acc[i][j] = __builtin_amdgcn_mfma_f32_16x16x32_bf16(
                    af[i], bfv[j], acc[i][j], 0, 0, 0);
        __syncthreads();
    }
#undef STAGE

    #pragma unroll
    for (int i = 0; i < 4; i++) {
        #pragma unroll
        for (int rr = 0; rr < 4; rr++) {
            int m = bm + wm + i * 16 + q * 4 + rr;
            #pragma unroll
            for (int j = 0; j < 4; j++) {
                int n = bn + wn + j * 16 + r16;
                float v = acc[i][j][rr];
                if (bias) v += bias[n];
                if (add) {
                    float a = add[(size_t)m * ldadd + n];
                    if (clip_add) a = clamp3(a, -10.f, 10.f);
                    v += a;
                }
                if (out_bf16)
                    ((unsigned short*)C)[(size_t)m * ldc + n] = f2bf(v);
                else
                    ((float*)C)[(size_t)m * ldc + n] = v;
            }
        }
    }
}

// ---------------------------------------------------------------------------
// Skinny MFMA GEMM: BC[rows,32] = xc_bf[rows,1024] @ W_x_bf[32,1024]^T.
// ---------------------------------------------------------------------------
__global__ __launch_bounds__(256) void gemm_bc(
    const unsigned short* __restrict__ A, const unsigned short* __restrict__ Bw,
    float* __restrict__ C)
{
    const int tid = threadIdx.x;
    const int wv  = tid >> 6;
    const int l   = tid & 63;
    const int r16 = l & 15;
    const int q   = l >> 4;
    const int row0 = blockIdx.x * 64 + wv * 16;

    const unsigned short* ap  = A  + (size_t)(row0 + r16) * 1024 + q * 8;
    const unsigned short* bp0 = Bw + (size_t)r16 * 1024 + q * 8;
    const unsigned short* bp1 = Bw + (size_t)(16 + r16) * 1024 + q * 8;

    f32x4 acc0 = {0.f, 0.f, 0.f, 0.f}, acc1 = {0.f, 0.f, 0.f, 0.f};
    #pragma unroll 4
    for (int k = 0; k < 1024; k += 32) {
        short8 af = *(const short8*)(ap + k);
        short8 b0 = *(const short8*)(bp0 + k);
        short8 b1 = *(const short8*)(bp1 + k);
        acc0 = __builtin_amdgcn_mfma_f32_16x16x32_bf16(af, b0, acc0, 0, 0, 0);
        acc1 = __builtin_amdgcn_mfma_f32_16x16x32_bf16(af, b1, acc1, 0, 0, 0);
    }
    #pragma unroll
    for (int rr = 0; rr < 4; rr++) {
        int m = row0 + q * 4 + rr;
        C[(size_t)m * 32 + r16]      = acc0[rr];
        C[(size_t)m * 32 + 16 + r16] = acc1[rr];
    }
}

// ---------------------------------------------------------------------------
// Depthwise causal conv (width 4) + bias + SiLU; bf16 input, 4 ch/thread.
// ---------------------------------------------------------------------------
__global__ __launch_bounds__(256) void conv_silu(
    const unsigned short* __restrict__ xp, const float* __restrict__ cw,
    const float* __restrict__ cb, unsigned short* __restrict__ xc)
{
    int idx = blockIdx.x * 256 + threadIdx.x;
    int c4 = (idx & 255) << 2;
    int bt = idx >> 8;
    int t  = bt & (SEQ - 1);

    float4 acc = *(const float4*)(cb + c4);
    float4 w0 = *(const float4*)(cw + (c4 + 0) * 4);
    float4 w1 = *(const float4*)(cw + (c4 + 1) * 4);
    float4 w2 = *(const float4*)(cw + (c4 + 2) * 4);
    float4 w3 = *(const float4*)(cw + (c4 + 3) * 4);

    #pragma unroll
    for (int k = 0; k < D_CONV; k++) {
        int tt = t - (D_CONV - 1) + k;
        if (tt >= 0) {
            ushort4 xv = *(const ushort4*)(xp + (size_t)(bt - (D_CONV - 1) + k) * 2048 + c4);
            acc.x += bf2f(xv.x) * ((const float*)&w0)[k];
            acc.y += bf2f(xv.y) * ((const float*)&w1)[k];
            acc.z += bf2f(xv.z) * ((const float*)&w2)[k];
            acc.w += bf2f(xv.w) * ((const float*)&w3)[k];
        }
    }
    ushort4 o;
    o.x = f2bf(silu(acc.x));
    o.y = f2bf(silu(acc.y));
    o.z = f2bf(silu(acc.z));
    o.w = f2bf(silu(acc.w));
    *(ushort4*)(xc + (size_t)bt * 1024 + c4) = o;
}

// ---------------------------------------------------------------------------
// Segmented scan phase A. One wave per (b, seg, 64-channel group).
// SEGLEN=32, bf16 dt/u, BC staged in LDS, 4-deep register pipeline.
// __launch_bounds__(64,4) caps VGPR at 128 -> 4 resident waves/SIMD.
// ---------------------------------------------------------------------------
__global__ __launch_bounds__(64, 4) void scan_phaseA(
    const unsigned short* __restrict__ xpres, const float* __restrict__ BC,
    const unsigned short* __restrict__ xc, const float* __restrict__ A_log,
    float* __restrict__ stA, float* __restrict__ prA)
{
    __shared__ float bc_lds[SEGLEN][32];      // 4 KB
    const int bx = blockIdx.x;
    const int seg = bx & (NSEG - 1);
    const int dg  = (bx >> 6) & 15;
    const int b   = bx >> 10;
    if (seg == NSEG - 1) return;
    const int lane = threadIdx.x;
    const int d = dg * 64 + lane;
    const float CL = 5.f * LOG2E;

    const size_t rowbase = (size_t)b * SEQ + (size_t)seg * SEGLEN;
    const float* BCp = BC + rowbase * 32;

    // stage the 32x32 BC tile (4 KB) into LDS
    #pragma unroll
    for (int c = 0; c < 4; c++)
        async_g2l(BCp + c * 256 + lane * 4,
                  (char*)&bc_lds[0][0] + c * 1024 + lane * 16);

    float A2[16];
    #pragma unroll
    for (int n = 0; n < 16; n++) A2[n] = A_log[n] * LOG2E;

    const unsigned short* dtp = xpres + rowbase * 2048 + d;
    const unsigned short* up  = xc + rowbase * 1024 + d;

    float st[16] = {};
    float se[16] = {};
    unsigned short dta[4], dtb[4], ua[4], ub[4];

#define LOADGA(g, dt_, u_) { \
        _Pragma("unroll") for (int jj = 0; jj < 4; ++jj) { \
            const int t_ = (g) * 4 + jj; \
            dt_[jj] = dtp[(size_t)t_ * 2048]; \
            u_[jj]  = up[(size_t)t_ * 1024]; \
        } }

#define COMPGA(g, dt_, u_) { \
        _Pragma("unroll") for (int jj = 0; jj < 4; ++jj) { \
            const int t_ = (g) * 4 + jj; \
            const float dtv_ = bf2f(dt_[jj]); \
            const float du_ = dtv_ * bf2f(u_[jj]); \
            float Bv_[16]; \
            _Pragma("unroll") for (int n = 0; n < 4; ++n) \
                *(float4*)&Bv_[n * 4] = *(const float4*)&bc_lds[t_][n * 4]; \
            _Pragma("unroll") for (int n = 0; n < 16; ++n) { \
                const float e_ = clamp3(dtv_ * A2[n], -CL, CL); \
                se[n] += e_; \
                st[n] = fast_exp2(e_) * st[n] + du_ * Bv_[n]; \
            } } }

    LOADGA(0, dta, ua);
    __syncthreads();   // drains vmcnt: BC tile + group 0 resident

    for (int g = 0; g < 8; g += 2) {
        LOADGA(g + 1, dtb, ub);
        COMPGA(g, dta, ua);
        if (g + 2 < 8) LOADGA(g + 2, dta, ua);
        COMPGA(g + 1, dtb, ub);
    }
#undef LOADGA
#undef COMPGA

    size_t o = (((size_t)b * NSEG + seg) * 1024 + d) * 16;
    #pragma unroll
    for (int n4 = 0; n4 < 4; n4++) {
        *(float4*)(stA + o + n4 * 4) = *(float4*)&st[n4 * 4];
        float4 pv;
        pv.x = fast_exp2(clamp3(se[n4 * 4 + 0], -115.41f, 115.41f));
        pv.y = fast_exp2(clamp3(se[n4 * 4 + 1], -115.41f, 115.41f));
        pv.z = fast_exp2(clamp3(se[n4 * 4 + 2], -115.41f, 115.41f));
        pv.w = fast_exp2(clamp3(se[n4 * 4 + 3], -115.41f, 115.41f));
        *(float4*)(prA + o + n4 * 4) = pv;
    }
}

// ---------------------------------------------------------------------------
// Phase B: sequential combine; stIn written in place over stA.
// ---------------------------------------------------------------------------
__global__ __launch_bounds__(256) void scan_combine(
    float* __restrict__ stA, const float* __restrict__ prA, int total)
{
    int idx = blockIdx.x * 256 + threadIdx.x;
    if (idx >= total) return;
    int dn = idx & 16383;
    int b  = idx >> 14;
    float prev = 0.f;
    #pragma unroll 4
    for (int s = 0; s < NSEG; s++) {
        size_t o = ((size_t)b * NSEG + s) * 16384 + dn;
        float a = stA[o], pr = prA[o];
        stA[o] = prev;
        prev = a + pr * prev;
    }
}

// ---------------------------------------------------------------------------
// Phase C: re-run segments with correct init; emit gated output.
// Bv/Cv share one 16-reg block (two passes over n) to stay under 128 VGPR.
// ---------------------------------------------------------------------------
__global__ __launch_bounds__(64, 4) void scan_phaseC(
    const unsigned short* __restrict__ xpres, const float* __restrict__ BC,
    const unsigned short* __restrict__ xc, const float* __restrict__ A_log,
    const float* __restrict__ Dvec, const float* __restrict__ stIn,
    unsigned short* __restrict__ y_bf)
{
    __shared__ float bc_lds[SEGLEN][32];      // 4 KB
    const int bx = blockIdx.x;
    const int seg = bx & (NSEG - 1);
    const int dg  = (bx >> 6) & 15;
    const int b   = bx >> 10;
    const int lane = threadIdx.x;
    const int d = dg * 64 + lane;
    const float CL = 5.f * LOG2E;

    const size_t rowbase = (size_t)b * SEQ + (size_t)seg * SEGLEN;
    const float* BCp = BC + rowbase * 32;

    #pragma unroll
    for (int c = 0; c < 4; c++)
        async_g2l(BCp + c * 256 + lane * 4,
                  (char*)&bc_lds[0][0] + c * 1024 + lane * 16);

    float A2[16];
    #pragma unroll
    for (int n = 0; n < 16; n++) A2[n] = A_log[n] * LOG2E;
    const float Dp = Dvec[d];

    const unsigned short* dtp  = xpres + rowbase * 2048 + d;
    const unsigned short* resp = xpres + rowbase * 2048 + 1024 + d;
    const unsigned short* up   = xc + rowbase * 1024 + d;
    unsigned short* yp = y_bf + rowbase * 1024 + d;

    float st[16];
    size_t o = (((size_t)b * NSEG + seg) * 1024 + d) * 16;
    #pragma unroll
    for (int n4 = 0; n4 < 4; n4++)
        *(float4*)&st[n4 * 4] = *(const float4*)(stIn + o + n4 * 4);

    unsigned short dta[4], dtb[4], ua[4], ub[4], ra[4], rb[4];

#define LOADGC(g, dt_, r_, u_) { \
        _Pragma("unroll") for (int jj = 0; jj < 4; ++jj) { \
            const int t_ = (g) * 4 + jj; \
            dt_[jj] = dtp[(size_t)t_ * 2048]; \
            r_[jj]  = resp[(size_t)t_ * 2048]; \
            u_[jj]  = up[(size_t)t_ * 1024]; \
        } }

#define COMPGC(g, dt_, r_, u_) { \
        _Pragma("unroll") for (int jj = 0; jj < 4; ++jj) { \
            const int t_ = (g) * 4 + jj; \
            const float dtv_ = bf2f(dt_[jj]); \
            const float uu_ = bf2f(u_[jj]); \
            const float du_ = dtv_ * uu_; \
            float V_[16]; \
            _Pragma("unroll") for (int n = 0; n < 4; ++n) \
                *(float4*)&V_[n * 4] = *(const float4*)&bc_lds[t_][n * 4]; \
            _Pragma("unroll") for (int n = 0; n < 16; ++n) { \
                const float e_ = clamp3(dtv_ * A2[n], -CL, CL); \
                st[n] = fast_exp2(e_) * st[n] + du_ * V_[n]; \
            } \
            _Pragma("unroll") for (int n = 0; n < 4; ++n) \
                *(float4*)&V_[n * 4] = *(const float4*)&bc_lds[t_][16 + n * 4]; \
            float y_ = 0.f; \
            _Pragma("unroll") for (int n = 0; n < 16; ++n) \
                y_ += st[n] * V_[n]; \
            const float outv_ = (y_ + uu_ * Dp) * silu(bf2f(r_[jj])); \
            yp[(size_t)t_ * 1024] = f2bf(outv_); \
        } }

    LOADGC(0, dta, ra, ua);
    __syncthreads();

    for (int g = 0; g < 8; g += 2) {
        LOADGC(g + 1, dtb, rb, ub);
        COMPGC(g, dta, ra, ua);
        if (g + 2 < 8) LOADGC(g + 2, dta, ra, ua);
        COMPGC(g + 1, dtb, rb, ub);
    }
#undef LOADGC
#undef COMPGC
}

// ---------------------------------------------------------------------------
// LayerNorm over last dim (512), eps 1e-5, in-place.
// ---------------------------------------------------------------------------
__global__ __launch_bounds__(128) void ln_kernel(
    float* __restrict__ out, const float* __restrict__ g,
    const float* __restrict__ bta)
{
    const int row = blockIdx.x;
    float* p = out + (size_t)row * D_MODEL;
    const int tid = threadIdx.x;

    float4 v = ((const float4*)p)[tid];
    float s1 = v.x + v.y + v.z + v.w;
    float s2 = v.x * v.x + v.y * v.y + v.z * v.z + v.w * v.w;
    #pragma unroll
    for (int off = 32; off > 0; off >>= 1) {
        s1 += __shfl_xor(s1, off);
        s2 += __shfl_xor(s2, off);
    }
    __shared__ float r1[2], r2[2];
    if ((tid & 63) == 0) { r1[tid >> 6] = s1; r2[tid >> 6] = s2; }
    __syncthreads();
    s1 = r1[0] + r1[1];
    s2 = r2[0] + r2[1];

    const float mu  = s1 * (1.f / D_MODEL);
    const float var = s2 * (1.f / D_MODEL) - mu * mu;
    const float rstd = rsqrtf(var + 1e-5f);

    float4 gg = ((const float4*)g)[tid];
    float4 bb = ((const float4*)bta)[tid];
    float4 o;
    o.x = (v.x - mu) * rstd * gg.x + bb.x;
    o.y = (v.y - mu) * rstd * gg.y + bb.y;
    o.z = (v.z - mu) * rstd * gg.z + bb.z;
    o.w = (v.w - mu) * rstd * gg.w + bb.w;
    ((float4*)p)[tid] = o;
}

// ---------------------------------------------------------------------------
extern "C" void kernel_launch(void* const* d_in, const int* in_sizes, int n_in,
                              void* d_out, int out_size, void* d_ws, size_t ws_size,
                              hipStream_t stream)
{
    const float* x      = (const float*)d_in[0];
    const float* W_in   = (const float*)d_in[1];
    const float* conv_w = (const float*)d_in[2];
    const float* conv_b = (const float*)d_in[3];
    const float* W_x    = (const float*)d_in[4];
    const float* W_dt   = (const float*)d_in[5];
    const float* b_dt   = (const float*)d_in[6];
    const float* A_log  = (const float*)d_in[7];
    const float* Dv     = (const float*)d_in[8];
    const float* W_out  = (const float*)d_in[9];
    const float* ln_g   = (const float*)d_in[10];
    const float* ln_b   = (const float*)d_in[11];
    float* out = (float*)d_out;

    // ---- fixed workspace: bf16 weights ----
    const size_t szWin  = (size_t)2048 * 512;
    const size_t szWdt  = (size_t)1024 * 1024;
    const size_t szWout = (size_t)512 * 1024;
    const size_t szWx   = (size_t)32 * 1024;
    char* p = (char*)d_ws;
    unsigned short* Wib  = (unsigned short*)p; p += szWin * 2;
    unsigned short* Wdtb = (unsigned short*)p; p += szWdt * 2;
    unsigned short* Wob  = (unsigned short*)p; p += szWout * 2;
    unsigned short* Wxb  = (unsigned short*)p; p += szWx * 2;
    const size_t fixed_bytes = (size_t)(p - (char*)d_ws);

    const size_t per_batch =
        (size_t)SEQ * 2048 * 2            // xpres bf16: [xp|res], xp later overwritten by dt
      + (size_t)SEQ * 1024 * 2            // ybuf (aliases x_bf)
      + (size_t)SEQ * 1024 * 2            // xc_bf
      + (size_t)SEQ * 32 * 4              // BC
      + (size_t)2 * NSEG * 1024 * 16 * 4; // stA + prA
    int cb = 16;
    while (cb > 1 && fixed_bytes + (size_t)cb * per_batch > ws_size) cb >>= 1;
    const int Mc = cb * SEQ;

    unsigned short* xpres = (unsigned short*)p; p += (size_t)Mc * 2048 * 2;
    unsigned short* ybuf  = (unsigned short*)p; p += (size_t)Mc * 1024 * 2;
    unsigned short* x_bf  = ybuf;               // dead before ybuf is written
    unsigned short* xc_bf = (unsigned short*)p; p += (size_t)Mc * 1024 * 2;
    float*          BCb   = (float*)p;          p += (size_t)Mc * 32 * 4;
    float*          stA   = (float*)p;          p += (size_t)cb * NSEG * 16384 * 4;
    float*          prA   = (float*)p;

    cast_bf16<<<(int)(szWin / 4 + 255) / 256, 256, 0, stream>>>((const float4*)W_in,  (ushort4*)Wib,  (int)(szWin / 4), 0);
    cast_bf16<<<(int)(szWdt / 4 + 255) / 256, 256, 0, stream>>>((const float4*)W_dt,  (ushort4*)Wdtb, (int)(szWdt / 4), 0);
    cast_bf16<<<(int)(szWout / 4 + 255) / 256, 256, 0, stream>>>((const float4*)W_out, (ushort4*)Wob, (int)(szWout / 4), 0);
    cast_bf16<<<(int)(szWx / 4 + 255) / 256, 256, 0, stream>>>((const float4*)W_x,   (ushort4*)Wxb,  (int)(szWx / 4), 0);

    for (int b0 = 0; b0 < B_SZ; b0 += cb) {
        const float* xk   = x   + (size_t)b0 * SEQ * D_MODEL;
        float*       outk = out + (size_t)b0 * SEQ * D_MODEL;

        // 0) x -> bf16 with clip
        cast_bf16<<<(Mc * 512 / 4) / 256, 256, 0, stream>>>(
            (const float4*)xk, (ushort4*)x_bf, Mc * 512 / 4, 1);

        // 1) xpres = clip(x) @ W_in^T  (bf16 out; N=2048 -> nbn_shift=4)
        gemm_bf16<<<(2048 / 128) * (Mc / 128), 256, 0, stream>>>(
            x_bf, Wib, xpres, 512, 2048, 4, nullptr, nullptr, 0, 0, 1);

        // 2) xc_bf = silu(conv(x_p) + conv_b)
        conv_silu<<<Mc, 256, 0, stream>>>(xpres, conv_w, conv_b, xc_bf);

        // 3) BC = xc @ W_x^T
        gemm_bc<<<Mc / 64, 256, 0, stream>>>(xc_bf, Wxb, BCb);

        // 4) dt = xc @ W_dt^T + b_dt -> xpres cols 0..1023 (bf16; shift=3)
        gemm_bf16<<<(1024 / 128) * (Mc / 128), 256, 0, stream>>>(
            xc_bf, Wdtb, xpres, 1024, 2048, 3, b_dt, nullptr, 0, 0, 1);

        // 5) segmented scan
        scan_phaseA<<<cb * NSEG * 16, 64, 0, stream>>>(xpres, BCb, xc_bf, A_log, stA, prA);
        scan_combine<<<(cb * 16384 + 255) / 256, 256, 0, stream>>>(stA, prA, cb * 16384);
        scan_phaseC<<<cb * NSEG * 16, 64, 0, stream>>>(xpres, BCb, xc_bf, A_log, Dv, stA, ybuf);

        // 6) out = y @ W_out^T + clip(x)   (f32 out; N=512 -> shift=2)
        gemm_bf16<<<(512 / 128) * (Mc / 128), 256, 0, stream>>>(
            ybuf, Wob, outk, 1024, 512, 2, nullptr, xk, 512, 1, 0);

        // 7) LayerNorm in-place
        ln_kernel<<<Mc, 128, 0, stream>>>(outk, ln_g, ln_b);
    }
}

// Round 3
// 875.844 us; speedup vs baseline: 1.1013x; 1.1013x over previous
//
#include <hip/hip_runtime.h>
#include <hip/hip_bf16.h>
#include <math.h>

#define B_SZ 16
#define SEQ 2048
#define D_MODEL 512
#define D_INNER 1024
#define D_STATE 16
#define D_CONV 4
#define NSEG 64
#define SEGLEN (SEQ / NSEG)   // 32
#define LOG2E 1.44269504f

typedef __attribute__((ext_vector_type(8))) short short8;
typedef __attribute__((ext_vector_type(4))) float f32x4;
typedef const __attribute__((address_space(1))) void* gas_ptr;
typedef __attribute__((address_space(3))) void* las_ptr;

__device__ __forceinline__ float bf2f(unsigned int bits16) {
    union { unsigned int i; float f; } v; v.i = bits16 << 16; return v.f;
}
__device__ __forceinline__ unsigned short f2bf(float f) {
    union { float f; unsigned int i; } v; v.f = f;
    unsigned int r = v.i + 0x7FFFu + ((v.i >> 16) & 1u);
    return (unsigned short)(r >> 16);
}
__device__ __forceinline__ void async_g2l(const void* g, void* l) {
    __builtin_amdgcn_global_load_lds((gas_ptr)g, (las_ptr)l, 16, 0, 0);
}
__device__ __forceinline__ float fast_exp2(float x) { return __builtin_amdgcn_exp2f(x); }
__device__ __forceinline__ float fast_rcp(float x)  { return __builtin_amdgcn_rcpf(x); }
__device__ __forceinline__ float clamp3(float x, float lo, float hi) {
    return __builtin_amdgcn_fmed3f(x, lo, hi);
}
__device__ __forceinline__ float silu(float x) {
    return x * fast_rcp(1.f + fast_exp2(-x * LOG2E));
}
// counted vmcnt waits (per-wave; loads retire in order)
__device__ __forceinline__ void vm_wait0() { asm volatile("s_waitcnt vmcnt(0)" ::: "memory"); }
__device__ __forceinline__ void vm_wait3() { asm volatile("s_waitcnt vmcnt(3)" ::: "memory"); }
__device__ __forceinline__ void vm_wait4() { asm volatile("s_waitcnt vmcnt(4)" ::: "memory"); }

// ---------------------------------------------------------------------------
// f32 -> bf16 cast (4 elements/thread), optional clip to [-10,10]
// ---------------------------------------------------------------------------
__global__ __launch_bounds__(256) void cast_bf16(
    const float4* __restrict__ in, ushort4* __restrict__ out, int n4, int do_clip)
{
    int i = blockIdx.x * 256 + threadIdx.x;
    if (i >= n4) return;
    float4 v = in[i];
    if (do_clip) {
        v.x = clamp3(v.x, -10.f, 10.f);
        v.y = clamp3(v.y, -10.f, 10.f);
        v.z = clamp3(v.z, -10.f, 10.f);
        v.w = clamp3(v.w, -10.f, 10.f);
    }
    ushort4 o;
    o.x = f2bf(v.x); o.y = f2bf(v.y); o.z = f2bf(v.z); o.w = f2bf(v.w);
    out[i] = o;
}

// ---------------------------------------------------------------------------
// BIG bf16 MFMA NT-GEMM: C[M,N] = A[M,K] @ Bw[N,K]^T.
// BM=256 x BN=128 tile, BK=32, 8 waves (4x2 grid of 64x64), 512 threads.
// 3-stage LDS pipeline with COUNTED vmcnt: each iter waits only its own
// tile-k loads (vmcnt(3)) before the raw s_barrier; tile-k+1's loads stay
// in flight across the barrier; tile k+2 is staged after the barrier that
// proves buffer (k+2)%3 is no longer being read. No vmcnt(0) drain in the
// main loop. XCD-aware swizzle (requires (M/256)%8==0) + XOR 16B-slot LDS
// swizzle (2-way, free). Epilogue: +bias[n], +add (opt clip), f32/bf16 out.
// ---------------------------------------------------------------------------
__global__ __launch_bounds__(512, 4) void gemm_big(
    const unsigned short* __restrict__ A, const unsigned short* __restrict__ Bw,
    void* __restrict__ C, int K, int ldc, int nbn_shift,
    const float* __restrict__ bias,
    const float* __restrict__ add, int ldadd, int clip_add, int out_bf16)
{
    __shared__ unsigned short As[3][256][32];   // 48 KB
    __shared__ unsigned short Bs[3][128][32];   // 24 KB
    const int h = blockIdx.x;
    const int xk = h & 7;
    const int qb = h >> 3;
    const int bn = (qb & ((1 << nbn_shift) - 1)) * 128;
    const int bm = ((qb >> nbn_shift) * 8 + xk) * 256;
    const int tid = threadIdx.x;
    const int wv = tid >> 6;          // 0..7
    const int l  = tid & 63;
    const int lr = l >> 2;            // staging row within 16-row chunk
    const int lc = l & 3;             // staging slot (fixed by lane)
    const int wm = (wv >> 1) * 64;    // 0,64,128,192
    const int wn = (wv & 1) * 64;     // 0,64
    const int r16 = l & 15;
    const int q   = l >> 4;
    const int gsw = (lc - ((lr >> 1) & 3)) & 3;
    const int ssw = ((q + ((r16 >> 1) & 3)) & 3) * 8;

    f32x4 acc[4][4];
    #pragma unroll
    for (int i = 0; i < 4; i++)
        #pragma unroll
        for (int j = 0; j < 4; j++)
            acc[i][j] = (f32x4){0.f, 0.f, 0.f, 0.f};

#define STAGEB(kk, bb) { \
        const int k0_ = (kk) * 32; \
        _Pragma("unroll") \
        for (int p_ = 0; p_ < 2; p_++) { \
            const int arow_ = wv * 32 + p_ * 16 + lr; \
            async_g2l((const char*)A + (((size_t)(bm + arow_)) * K + k0_ + gsw * 8) * 2, \
                      (char*)&As[bb][wv * 32 + p_ * 16][0]); \
        } \
        const int brow_ = wv * 16 + lr; \
        async_g2l((const char*)Bw + (((size_t)(bn + brow_)) * K + k0_ + gsw * 8) * 2, \
                  (char*)&Bs[bb][wv * 16][0]); \
    }

    const int nk = K >> 5;            // >= 16 for all our shapes
    STAGEB(0, 0);
    STAGEB(1, 1);
    int c0 = 0, c1 = 1, c2 = 2;       // buf holding tiles kk, kk+1, kk+2

    for (int kk = 0; kk < nk; kk++) {
        if (kk + 1 < nk) vm_wait3(); else vm_wait0();
        __builtin_amdgcn_s_barrier();     // all waves: tile kk resident

        short8 af[4], bfv[4];
        #pragma unroll
        for (int i = 0; i < 4; i++) {
            af[i]  = *(const short8*)&As[c0][wm + i * 16 + r16][ssw];
            bfv[i] = *(const short8*)&Bs[c0][wn + i * 16 + r16][ssw];
        }
        if (kk + 2 < nk) STAGEB(kk + 2, c2);

        #pragma unroll
        for (int i = 0; i < 4; i++)
            #pragma unroll
            for (int j = 0; j < 4; j++)
                acc[i][j] = __builtin_amdgcn_mfma_f32_16x16x32_bf16(
                    af[i], bfv[j], acc[i][j], 0, 0, 0);

        int t = c0; c0 = c1; c1 = c2; c2 = t;
    }
#undef STAGEB

    #pragma unroll
    for (int i = 0; i < 4; i++) {
        #pragma unroll
        for (int rr = 0; rr < 4; rr++) {
            int m = bm + wm + i * 16 + q * 4 + rr;
            #pragma unroll
            for (int j = 0; j < 4; j++) {
                int n = bn + wn + j * 16 + r16;
                float v = acc[i][j][rr];
                if (bias) v += bias[n];
                if (add) {
                    float a = add[(size_t)m * ldadd + n];
                    if (clip_add) a = clamp3(a, -10.f, 10.f);
                    v += a;
                }
                if (out_bf16)
                    ((unsigned short*)C)[(size_t)m * ldc + n] = f2bf(v);
                else
                    ((float*)C)[(size_t)m * ldc + n] = v;
            }
        }
    }
}

// ---------------------------------------------------------------------------
// 128x128 bf16 MFMA NT-GEMM (4 waves), 3-stage counted-vmcnt pipeline.
// Used for the skinny-N output GEMM (N=512). Requires (M/128)%8==0.
// ---------------------------------------------------------------------------
__global__ __launch_bounds__(256) void gemm_bf16(
    const unsigned short* __restrict__ A, const unsigned short* __restrict__ Bw,
    void* __restrict__ C, int K, int ldc, int nbn_shift,
    const float* __restrict__ bias,
    const float* __restrict__ add, int ldadd, int clip_add, int out_bf16)
{
    __shared__ unsigned short As[3][128][32];   // 24 KB
    __shared__ unsigned short Bs[3][128][32];   // 24 KB
    const int h = blockIdx.x;
    const int xk = h & 7;
    const int qb = h >> 3;
    const int bn = (qb & ((1 << nbn_shift) - 1)) * 128;
    const int bm = ((qb >> nbn_shift) * 8 + xk) * 128;
    const int tid = threadIdx.x;
    const int wv = tid >> 6;
    const int l  = tid & 63;
    const int lr = l >> 2;
    const int lc = l & 3;
    const int wm = (wv >> 1) * 64;
    const int wn = (wv & 1) * 64;
    const int r16 = l & 15;
    const int q   = l >> 4;
    const int gsw = (lc - ((lr >> 1) & 3)) & 3;
    const int ssw = ((q + ((r16 >> 1) & 3)) & 3) * 8;

    f32x4 acc[4][4];
    #pragma unroll
    for (int i = 0; i < 4; i++)
        #pragma unroll
        for (int j = 0; j < 4; j++)
            acc[i][j] = (f32x4){0.f, 0.f, 0.f, 0.f};

#define STAGE(kk, bb) { \
        const int k0_ = (kk) * 32; \
        _Pragma("unroll") \
        for (int p_ = 0; p_ < 2; p_++) { \
            const int row_ = wv * 32 + p_ * 16 + lr; \
            async_g2l((const char*)A + (((size_t)(bm + row_)) * K + k0_ + gsw * 8) * 2, \
                      (char*)&As[bb][wv * 32 + p_ * 16][0]); \
            async_g2l((const char*)Bw + (((size_t)(bn + row_)) * K + k0_ + gsw * 8) * 2, \
                      (char*)&Bs[bb][wv * 32 + p_ * 16][0]); \
        } }

    const int nk = K >> 5;
    STAGE(0, 0);
    STAGE(1, 1);
    int c0 = 0, c1 = 1, c2 = 2;

    for (int kk = 0; kk < nk; kk++) {
        if (kk + 1 < nk) vm_wait4(); else vm_wait0();
        __builtin_amdgcn_s_barrier();

        short8 af[4], bfv[4];
        #pragma unroll
        for (int i = 0; i < 4; i++) {
            af[i]  = *(const short8*)&As[c0][wm + i * 16 + r16][ssw];
            bfv[i] = *(const short8*)&Bs[c0][wn + i * 16 + r16][ssw];
        }
        if (kk + 2 < nk) STAGE(kk + 2, c2);

        #pragma unroll
        for (int i = 0; i < 4; i++)
            #pragma unroll
            for (int j = 0; j < 4; j++)
                acc[i][j] = __builtin_amdgcn_mfma_f32_16x16x32_bf16(
                    af[i], bfv[j], acc[i][j], 0, 0, 0);

        int t = c0; c0 = c1; c1 = c2; c2 = t;
    }
#undef STAGE

    #pragma unroll
    for (int i = 0; i < 4; i++) {
        #pragma unroll
        for (int rr = 0; rr < 4; rr++) {
            int m = bm + wm + i * 16 + q * 4 + rr;
            #pragma unroll
            for (int j = 0; j < 4; j++) {
                int n = bn + wn + j * 16 + r16;
                float v = acc[i][j][rr];
                if (bias) v += bias[n];
                if (add) {
                    float a = add[(size_t)m * ldadd + n];
                    if (clip_add) a = clamp3(a, -10.f, 10.f);
                    v += a;
                }
                if (out_bf16)
                    ((unsigned short*)C)[(size_t)m * ldc + n] = f2bf(v);
                else
                    ((float*)C)[(size_t)m * ldc + n] = v;
            }
        }
    }
}

// ---------------------------------------------------------------------------
// Skinny MFMA GEMM: BC[rows,32] = xc_bf[rows,1024] @ W_x_bf[32,1024]^T.
// ---------------------------------------------------------------------------
__global__ __launch_bounds__(256) void gemm_bc(
    const unsigned short* __restrict__ A, const unsigned short* __restrict__ Bw,
    float* __restrict__ C)
{
    const int tid = threadIdx.x;
    const int wv  = tid >> 6;
    const int l   = tid & 63;
    const int r16 = l & 15;
    const int q   = l >> 4;
    const int row0 = blockIdx.x * 64 + wv * 16;

    const unsigned short* ap  = A  + (size_t)(row0 + r16) * 1024 + q * 8;
    const unsigned short* bp0 = Bw + (size_t)r16 * 1024 + q * 8;
    const unsigned short* bp1 = Bw + (size_t)(16 + r16) * 1024 + q * 8;

    f32x4 acc0 = {0.f, 0.f, 0.f, 0.f}, acc1 = {0.f, 0.f, 0.f, 0.f};
    #pragma unroll 4
    for (int k = 0; k < 1024; k += 32) {
        short8 af = *(const short8*)(ap + k);
        short8 b0 = *(const short8*)(bp0 + k);
        short8 b1 = *(const short8*)(bp1 + k);
        acc0 = __builtin_amdgcn_mfma_f32_16x16x32_bf16(af, b0, acc0, 0, 0, 0);
        acc1 = __builtin_amdgcn_mfma_f32_16x16x32_bf16(af, b1, acc1, 0, 0, 0);
    }
    #pragma unroll
    for (int rr = 0; rr < 4; rr++) {
        int m = row0 + q * 4 + rr;
        C[(size_t)m * 32 + r16]      = acc0[rr];
        C[(size_t)m * 32 + 16 + r16] = acc1[rr];
    }
}

// ---------------------------------------------------------------------------
// Depthwise causal conv (width 4) + bias + SiLU; bf16 input, 4 ch/thread.
// ---------------------------------------------------------------------------
__global__ __launch_bounds__(256) void conv_silu(
    const unsigned short* __restrict__ xp, const float* __restrict__ cw,
    const float* __restrict__ cb, unsigned short* __restrict__ xc)
{
    int idx = blockIdx.x * 256 + threadIdx.x;
    int c4 = (idx & 255) << 2;
    int bt = idx >> 8;
    int t  = bt & (SEQ - 1);

    float4 acc = *(const float4*)(cb + c4);
    float4 w0 = *(const float4*)(cw + (c4 + 0) * 4);
    float4 w1 = *(const float4*)(cw + (c4 + 1) * 4);
    float4 w2 = *(const float4*)(cw + (c4 + 2) * 4);
    float4 w3 = *(const float4*)(cw + (c4 + 3) * 4);

    #pragma unroll
    for (int k = 0; k < D_CONV; k++) {
        int tt = t - (D_CONV - 1) + k;
        if (tt >= 0) {
            ushort4 xv = *(const ushort4*)(xp + (size_t)(bt - (D_CONV - 1) + k) * 2048 + c4);
            acc.x += bf2f(xv.x) * ((const float*)&w0)[k];
            acc.y += bf2f(xv.y) * ((const float*)&w1)[k];
            acc.z += bf2f(xv.z) * ((const float*)&w2)[k];
            acc.w += bf2f(xv.w) * ((const float*)&w3)[k];
        }
    }
    ushort4 o;
    o.x = f2bf(silu(acc.x));
    o.y = f2bf(silu(acc.y));
    o.z = f2bf(silu(acc.z));
    o.w = f2bf(silu(acc.w));
    *(ushort4*)(xc + (size_t)bt * 1024 + c4) = o;
}

// ---------------------------------------------------------------------------
// Segmented scan phase A. One wave per (b, seg, 64-channel group).
// ---------------------------------------------------------------------------
__global__ __launch_bounds__(64, 4) void scan_phaseA(
    const unsigned short* __restrict__ xpres, const float* __restrict__ BC,
    const unsigned short* __restrict__ xc, const float* __restrict__ A_log,
    float* __restrict__ stA, float* __restrict__ prA)
{
    __shared__ float bc_lds[SEGLEN][32];      // 4 KB
    const int bx = blockIdx.x;
    const int seg = bx & (NSEG - 1);
    const int dg  = (bx >> 6) & 15;
    const int b   = bx >> 10;
    if (seg == NSEG - 1) return;
    const int lane = threadIdx.x;
    const int d = dg * 64 + lane;
    const float CL = 5.f * LOG2E;

    const size_t rowbase = (size_t)b * SEQ + (size_t)seg * SEGLEN;
    const float* BCp = BC + rowbase * 32;

    #pragma unroll
    for (int c = 0; c < 4; c++)
        async_g2l(BCp + c * 256 + lane * 4,
                  (char*)&bc_lds[0][0] + c * 1024 + lane * 16);

    float A2[16];
    #pragma unroll
    for (int n = 0; n < 16; n++) A2[n] = A_log[n] * LOG2E;

    const unsigned short* dtp = xpres + rowbase * 2048 + d;
    const unsigned short* up  = xc + rowbase * 1024 + d;

    float st[16] = {};
    float se[16] = {};
    unsigned short dta[4], dtb[4], ua[4], ub[4];

#define LOADGA(g, dt_, u_) { \
        _Pragma("unroll") for (int jj = 0; jj < 4; ++jj) { \
            const int t_ = (g) * 4 + jj; \
            dt_[jj] = dtp[(size_t)t_ * 2048]; \
            u_[jj]  = up[(size_t)t_ * 1024]; \
        } }

#define COMPGA(g, dt_, u_) { \
        _Pragma("unroll") for (int jj = 0; jj < 4; ++jj) { \
            const int t_ = (g) * 4 + jj; \
            const float dtv_ = bf2f(dt_[jj]); \
            const float du_ = dtv_ * bf2f(u_[jj]); \
            float Bv_[16]; \
            _Pragma("unroll") for (int n = 0; n < 4; ++n) \
                *(float4*)&Bv_[n * 4] = *(const float4*)&bc_lds[t_][n * 4]; \
            _Pragma("unroll") for (int n = 0; n < 16; ++n) { \
                const float e_ = clamp3(dtv_ * A2[n], -CL, CL); \
                se[n] += e_; \
                st[n] = fast_exp2(e_) * st[n] + du_ * Bv_[n]; \
            } } }

    LOADGA(0, dta, ua);
    __syncthreads();

    for (int g = 0; g < 8; g += 2) {
        LOADGA(g + 1, dtb, ub);
        COMPGA(g, dta, ua);
        if (g + 2 < 8) LOADGA(g + 2, dta, ua);
        COMPGA(g + 1, dtb, ub);
    }
#undef LOADGA
#undef COMPGA

    size_t o = (((size_t)b * NSEG + seg) * 1024 + d) * 16;
    #pragma unroll
    for (int n4 = 0; n4 < 4; n4++) {
        *(float4*)(stA + o + n4 * 4) = *(float4*)&st[n4 * 4];
        float4 pv;
        pv.x = fast_exp2(clamp3(se[n4 * 4 + 0], -115.41f, 115.41f));
        pv.y = fast_exp2(clamp3(se[n4 * 4 + 1], -115.41f, 115.41f));
        pv.z = fast_exp2(clamp3(se[n4 * 4 + 2], -115.41f, 115.41f));
        pv.w = fast_exp2(clamp3(se[n4 * 4 + 3], -115.41f, 115.41f));
        *(float4*)(prA + o + n4 * 4) = pv;
    }
}

// ---------------------------------------------------------------------------
// Phase B: sequential combine; stIn written in place over stA.
// ---------------------------------------------------------------------------
__global__ __launch_bounds__(256) void scan_combine(
    float* __restrict__ stA, const float* __restrict__ prA, int total)
{
    int idx = blockIdx.x * 256 + threadIdx.x;
    if (idx >= total) return;
    int dn = idx & 16383;
    int b  = idx >> 14;
    float prev = 0.f;
    #pragma unroll 4
    for (int s = 0; s < NSEG; s++) {
        size_t o = ((size_t)b * NSEG + s) * 16384 + dn;
        float a = stA[o], pr = prA[o];
        stA[o] = prev;
        prev = a + pr * prev;
    }
}

// ---------------------------------------------------------------------------
// Phase C: re-run segments with correct init; emit gated output.
// ---------------------------------------------------------------------------
__global__ __launch_bounds__(64, 4) void scan_phaseC(
    const unsigned short* __restrict__ xpres, const float* __restrict__ BC,
    const unsigned short* __restrict__ xc, const float* __restrict__ A_log,
    const float* __restrict__ Dvec, const float* __restrict__ stIn,
    unsigned short* __restrict__ y_bf)
{
    __shared__ float bc_lds[SEGLEN][32];      // 4 KB
    const int bx = blockIdx.x;
    const int seg = bx & (NSEG - 1);
    const int dg  = (bx >> 6) & 15;
    const int b   = bx >> 10;
    const int lane = threadIdx.x;
    const int d = dg * 64 + lane;
    const float CL = 5.f * LOG2E;

    const size_t rowbase = (size_t)b * SEQ + (size_t)seg * SEGLEN;
    const float* BCp = BC + rowbase * 32;

    #pragma unroll
    for (int c = 0; c < 4; c++)
        async_g2l(BCp + c * 256 + lane * 4,
                  (char*)&bc_lds[0][0] + c * 1024 + lane * 16);

    float A2[16];
    #pragma unroll
    for (int n = 0; n < 16; n++) A2[n] = A_log[n] * LOG2E;
    const float Dp = Dvec[d];

    const unsigned short* dtp  = xpres + rowbase * 2048 + d;
    const unsigned short* resp = xpres + rowbase * 2048 + 1024 + d;
    const unsigned short* up   = xc + rowbase * 1024 + d;
    unsigned short* yp = y_bf + rowbase * 1024 + d;

    float st[16];
    size_t o = (((size_t)b * NSEG + seg) * 1024 + d) * 16;
    #pragma unroll
    for (int n4 = 0; n4 < 4; n4++)
        *(float4*)&st[n4 * 4] = *(const float4*)(stIn + o + n4 * 4);

    unsigned short dta[4], dtb[4], ua[4], ub[4], ra[4], rb[4];

#define LOADGC(g, dt_, r_, u_) { \
        _Pragma("unroll") for (int jj = 0; jj < 4; ++jj) { \
            const int t_ = (g) * 4 + jj; \
            dt_[jj] = dtp[(size_t)t_ * 2048]; \
            r_[jj]  = resp[(size_t)t_ * 2048]; \
            u_[jj]  = up[(size_t)t_ * 1024]; \
        } }

#define COMPGC(g, dt_, r_, u_) { \
        _Pragma("unroll") for (int jj = 0; jj < 4; ++jj) { \
            const int t_ = (g) * 4 + jj; \
            const float dtv_ = bf2f(dt_[jj]); \
            const float uu_ = bf2f(u_[jj]); \
            const float du_ = dtv_ * uu_; \
            float V_[16]; \
            _Pragma("unroll") for (int n = 0; n < 4; ++n) \
                *(float4*)&V_[n * 4] = *(const float4*)&bc_lds[t_][n * 4]; \
            _Pragma("unroll") for (int n = 0; n < 16; ++n) { \
                const float e_ = clamp3(dtv_ * A2[n], -CL, CL); \
                st[n] = fast_exp2(e_) * st[n] + du_ * V_[n]; \
            } \
            _Pragma("unroll") for (int n = 0; n < 4; ++n) \
                *(float4*)&V_[n * 4] = *(const float4*)&bc_lds[t_][16 + n * 4]; \
            float y_ = 0.f; \
            _Pragma("unroll") for (int n = 0; n < 16; ++n) \
                y_ += st[n] * V_[n]; \
            const float outv_ = (y_ + uu_ * Dp) * silu(bf2f(r_[jj])); \
            yp[(size_t)t_ * 1024] = f2bf(outv_); \
        } }

    LOADGC(0, dta, ra, ua);
    __syncthreads();

    for (int g = 0; g < 8; g += 2) {
        LOADGC(g + 1, dtb, rb, ub);
        COMPGC(g, dta, ra, ua);
        if (g + 2 < 8) LOADGC(g + 2, dta, ra, ua);
        COMPGC(g + 1, dtb, rb, ub);
    }
#undef LOADGC
#undef COMPGC
}

// ---------------------------------------------------------------------------
// LayerNorm over last dim (512), eps 1e-5, in-place.
// ---------------------------------------------------------------------------
__global__ __launch_bounds__(128) void ln_kernel(
    float* __restrict__ out, const float* __restrict__ g,
    const float* __restrict__ bta)
{
    const int row = blockIdx.x;
    float* p = out + (size_t)row * D_MODEL;
    const int tid = threadIdx.x;

    float4 v = ((const float4*)p)[tid];
    float s1 = v.x + v.y + v.z + v.w;
    float s2 = v.x * v.x + v.y * v.y + v.z * v.z + v.w * v.w;
    #pragma unroll
    for (int off = 32; off > 0; off >>= 1) {
        s1 += __shfl_xor(s1, off);
        s2 += __shfl_xor(s2, off);
    }
    __shared__ float r1[2], r2[2];
    if ((tid & 63) == 0) { r1[tid >> 6] = s1; r2[tid >> 6] = s2; }
    __syncthreads();
    s1 = r1[0] + r1[1];
    s2 = r2[0] + r2[1];

    const float mu  = s1 * (1.f / D_MODEL);
    const float var = s2 * (1.f / D_MODEL) - mu * mu;
    const float rstd = rsqrtf(var + 1e-5f);

    float4 gg = ((const float4*)g)[tid];
    float4 bb = ((const float4*)bta)[tid];
    float4 o;
    o.x = (v.x - mu) * rstd * gg.x + bb.x;
    o.y = (v.y - mu) * rstd * gg.y + bb.y;
    o.z = (v.z - mu) * rstd * gg.z + bb.z;
    o.w = (v.w - mu) * rstd * gg.w + bb.w;
    ((float4*)p)[tid] = o;
}

// ---------------------------------------------------------------------------
extern "C" void kernel_launch(void* const* d_in, const int* in_sizes, int n_in,
                              void* d_out, int out_size, void* d_ws, size_t ws_size,
                              hipStream_t stream)
{
    const float* x      = (const float*)d_in[0];
    const float* W_in   = (const float*)d_in[1];
    const float* conv_w = (const float*)d_in[2];
    const float* conv_b = (const float*)d_in[3];
    const float* W_x    = (const float*)d_in[4];
    const float* W_dt   = (const float*)d_in[5];
    const float* b_dt   = (const float*)d_in[6];
    const float* A_log  = (const float*)d_in[7];
    const float* Dv     = (const float*)d_in[8];
    const float* W_out  = (const float*)d_in[9];
    const float* ln_g   = (const float*)d_in[10];
    const float* ln_b   = (const float*)d_in[11];
    float* out = (float*)d_out;

    // ---- fixed workspace: bf16 weights ----
    const size_t szWin  = (size_t)2048 * 512;
    const size_t szWdt  = (size_t)1024 * 1024;
    const size_t szWout = (size_t)512 * 1024;
    const size_t szWx   = (size_t)32 * 1024;
    char* p = (char*)d_ws;
    unsigned short* Wib  = (unsigned short*)p; p += szWin * 2;
    unsigned short* Wdtb = (unsigned short*)p; p += szWdt * 2;
    unsigned short* Wob  = (unsigned short*)p; p += szWout * 2;
    unsigned short* Wxb  = (unsigned short*)p; p += szWx * 2;
    const size_t fixed_bytes = (size_t)(p - (char*)d_ws);

    const size_t per_batch =
        (size_t)SEQ * 2048 * 2            // xpres bf16: [xp|res], xp later overwritten by dt
      + (size_t)SEQ * 1024 * 2            // ybuf (aliases x_bf)
      + (size_t)SEQ * 1024 * 2            // xc_bf
      + (size_t)SEQ * 32 * 4              // BC
      + (size_t)2 * NSEG * 1024 * 16 * 4; // stA + prA
    int cb = 16;
    while (cb > 1 && fixed_bytes + (size_t)cb * per_batch > ws_size) cb >>= 1;
    const int Mc = cb * SEQ;

    unsigned short* xpres = (unsigned short*)p; p += (size_t)Mc * 2048 * 2;
    unsigned short* ybuf  = (unsigned short*)p; p += (size_t)Mc * 1024 * 2;
    unsigned short* x_bf  = ybuf;               // dead before ybuf is written
    unsigned short* xc_bf = (unsigned short*)p; p += (size_t)Mc * 1024 * 2;
    float*          BCb   = (float*)p;          p += (size_t)Mc * 32 * 4;
    float*          stA   = (float*)p;          p += (size_t)cb * NSEG * 16384 * 4;
    float*          prA   = (float*)p;

    cast_bf16<<<(int)(szWin / 4 + 255) / 256, 256, 0, stream>>>((const float4*)W_in,  (ushort4*)Wib,  (int)(szWin / 4), 0);
    cast_bf16<<<(int)(szWdt / 4 + 255) / 256, 256, 0, stream>>>((const float4*)W_dt,  (ushort4*)Wdtb, (int)(szWdt / 4), 0);
    cast_bf16<<<(int)(szWout / 4 + 255) / 256, 256, 0, stream>>>((const float4*)W_out, (ushort4*)Wob, (int)(szWout / 4), 0);
    cast_bf16<<<(int)(szWx / 4 + 255) / 256, 256, 0, stream>>>((const float4*)W_x,   (ushort4*)Wxb,  (int)(szWx / 4), 0);

    for (int b0 = 0; b0 < B_SZ; b0 += cb) {
        const float* xk   = x   + (size_t)b0 * SEQ * D_MODEL;
        float*       outk = out + (size_t)b0 * SEQ * D_MODEL;

        // 0) x -> bf16 with clip
        cast_bf16<<<(Mc * 512 / 4) / 256, 256, 0, stream>>>(
            (const float4*)xk, (ushort4*)x_bf, Mc * 512 / 4, 1);

        // 1) xpres = clip(x) @ W_in^T  (bf16 out; BM=256: grid = (N/128)*(Mc/256))
        gemm_big<<<16 * (Mc / 256), 512, 0, stream>>>(
            x_bf, Wib, xpres, 512, 2048, 4, nullptr, nullptr, 0, 0, 1);

        // 2) xc_bf = silu(conv(x_p) + conv_b)
        conv_silu<<<Mc, 256, 0, stream>>>(xpres, conv_w, conv_b, xc_bf);

        // 3) BC = xc @ W_x^T
        gemm_bc<<<Mc / 64, 256, 0, stream>>>(xc_bf, Wxb, BCb);

        // 4) dt = xc @ W_dt^T + b_dt -> xpres cols 0..1023 (bf16)
        gemm_big<<<8 * (Mc / 256), 512, 0, stream>>>(
            xc_bf, Wdtb, xpres, 1024, 2048, 3, b_dt, nullptr, 0, 0, 1);

        // 5) segmented scan
        scan_phaseA<<<cb * NSEG * 16, 64, 0, stream>>>(xpres, BCb, xc_bf, A_log, stA, prA);
        scan_combine<<<(cb * 16384 + 255) / 256, 256, 0, stream>>>(stA, prA, cb * 16384);
        scan_phaseC<<<cb * NSEG * 16, 64, 0, stream>>>(xpres, BCb, xc_bf, A_log, Dv, stA, ybuf);

        // 6) out = y @ W_out^T + clip(x)   (f32 out; 128^2 tile, N=512 -> shift=2)
        gemm_bf16<<<4 * (Mc / 128), 256, 0, stream>>>(
            ybuf, Wob, outk, 1024, 512, 2, nullptr, xk, 512, 1, 0);

        // 7) LayerNorm in-place
        ln_kernel<<<Mc, 128, 0, stream>>>(outk, ln_g, ln_b);
    }
}